// Round 1
// baseline (664.218 us; speedup 1.0000x reference)
//
#include <hip/hip_runtime.h>
#include <cstdint>
#include <cstddef>

// ============================================================================
// DualStateLinearAttention on MI355X — round 6
//  R5 counters: k_gemm_proj = 275us of 593 (MfmaUtil 26%, VALU 43%, HBM 14%)
//  -> the 1-phase stage/sync/compute GEMM structure is the bottleneck.
//  This round: 256^2-tile 4-phase-per-K-tile GEMM (T3+T4 counted vmcnt(4),
//  T5 setprio, proven gather-swizzle LDS kept). 8 waves, 128KB LDS dbuf,
//  1 block/CU. Staging of tile t+1 spread over tile t's phases; waits are
//  >=3 phases deep and never drain to 0 except the peeled last tile.
// Pipeline: cvt -> proj(5x fused) -> gc -> [sA -> s2 -> s3b] x2 -> out-GEMM.
// ============================================================================

#define BB     2
#define SEQ    2048
#define HIDN   2048
#define NH     16
#define DD     128
#define CHUNK  64
#define NCHUNK (SEQ / CHUNK)   // 32
#define NBH    (BB * NH)       // 32
#define NELC   8388608
#define WELC   4194304
static constexpr float QSCALE = 0.08838834764831845f;  // 128^-0.5

typedef __bf16 bf16_t;
typedef _Float16 half_t;
typedef short  short8 __attribute__((ext_vector_type(8)));
typedef float  f32x4  __attribute__((ext_vector_type(4)));

__device__ __forceinline__ float bf2f(short u) {
  return (float)__builtin_bit_cast(bf16_t, u);
}
__device__ __forceinline__ short f2bf(float f) {
  return __builtin_bit_cast(short, (bf16_t)f);
}
__device__ __forceinline__ float hf2f(short u) {
  return (float)__builtin_bit_cast(half_t, u);
}
__device__ __forceinline__ short f2hf(float f) {
  return __builtin_bit_cast(short, (half_t)f);
}

__device__ __forceinline__ void gload_lds16(const void* g, void* l) {
  __builtin_amdgcn_global_load_lds(
      (__attribute__((address_space(1))) unsigned int*)g,
      (__attribute__((address_space(3))) unsigned int*)l, 16, 0, 0);
}

#define VMW4 asm volatile("s_waitcnt vmcnt(4)" ::: "memory")
#define VMW2 asm volatile("s_waitcnt vmcnt(2)" ::: "memory")
#define VMW0 asm volatile("s_waitcnt vmcnt(0)" ::: "memory")
#define LGKM0 asm volatile("s_waitcnt lgkmcnt(0)" ::: "memory")
#define SBAR __builtin_amdgcn_s_barrier()

// ---------------------------------------------------------------------------
// 256x256 bf16 MFMA GEMM, BK=64, 4 phases/K-tile, counted vmcnt, setprio.
// LDS fragment swizzle: LDS chunk c of row r holds global chunk c^(r&7)
// (same involution on stage and read side -> ds_read_b128 conflict-free;
// identical to the R4-proven 128^2 layout).
// ---------------------------------------------------------------------------

// stage A rows {rb0, rb0+128} (pair0: rb0=0, pair1: rb0=64) of K-tile kt
#define STAGE_A(nx, kt, pair)                                              \
  {                                                                        \
    const int rb0 = (pair) ? 64 : 0;                                       \
    gload_lds16(Ag + (size_t)rb0 * HIDN + (size_t)(kt) * 64,               \
                (void*)&As[nx][(rb0 + wave * 8) * 64]);                    \
    gload_lds16(Ag + (size_t)(rb0 + 128) * HIDN + (size_t)(kt) * 64,       \
                (void*)&As[nx][(rb0 + 128 + wave * 8) * 64]);              \
  }

// stage B cols for n-half `pair`: rounds cover cols (2q+w2)*64+pair*32+w3*8
#define STAGE_B(nx, kt, pair)                                              \
  {                                                                        \
    const int cb0 = (wave >> 2) * 64 + (pair) * 32 + (wave & 3) * 8;       \
    gload_lds16(Bg + (size_t)cb0 * HIDN + (size_t)(kt) * 64,               \
                (void*)&Bs[nx][cb0 * 64]);                                 \
    gload_lds16(Bg + (size_t)(cb0 + 128) * HIDN + (size_t)(kt) * 64,       \
                (void*)&Bs[nx][(cb0 + 128) * 64]);                         \
  }

#define LOAD_A(mh)                                                         \
  {                                                                        \
    _Pragma("unroll") for (int f = 0; f < 4; f++) {                        \
      const int row = wm * 128 + (mh) * 64 + f * 16 + l16;                 \
      ar[f][0] = *(const short8*)&As[cur][row * 64 + ((qd ^ ro) << 3)];    \
      ar[f][1] =                                                           \
          *(const short8*)&As[cur][row * 64 + (((4 + qd) ^ ro) << 3)];     \
    }                                                                      \
  }

#define LOAD_B(nh)                                                         \
  {                                                                        \
    _Pragma("unroll") for (int g = 0; g < 2; g++) {                        \
      const int col = wn * 64 + (nh) * 32 + g * 16 + l16;                  \
      br[g][0] = *(const short8*)&Bs[cur][col * 64 + ((qd ^ ro) << 3)];    \
      br[g][1] =                                                           \
          *(const short8*)&Bs[cur][col * 64 + (((4 + qd) ^ ro) << 3)];     \
    }                                                                      \
  }

#define MFMA_Q(mh, nh)                                                     \
  {                                                                        \
    __builtin_amdgcn_s_setprio(1);                                         \
    _Pragma("unroll") for (int ks = 0; ks < 2; ks++)                       \
    _Pragma("unroll") for (int f = 0; f < 4; f++)                          \
    _Pragma("unroll") for (int g = 0; g < 2; g++)                          \
      acc[(mh) * 4 + f][(nh) * 2 + g] =                                    \
          __builtin_amdgcn_mfma_f32_16x16x32_bf16(                         \
              ar[f][ks], br[g][ks], acc[(mh) * 4 + f][(nh) * 2 + g],       \
              0, 0, 0);                                                    \
    __builtin_amdgcn_s_setprio(0);                                         \
  }

__device__ __forceinline__ void gemm256(const bf16_t* __restrict__ A,
                                        const bf16_t* __restrict__ Bw,
                                        const float*  __restrict__ bias,
                                        bf16_t* __restrict__ outb,
                                        float*  __restrict__ outf, int epi) {
  __shared__ short As[2][256 * 64];
  __shared__ short Bs[2][256 * 64];
  const int tm   = blockIdx.x * 256;
  const int tn   = blockIdx.y * 256;
  const int tid  = threadIdx.x;
  const int wave = tid >> 6;
  const int lane = tid & 63;
  const int wm   = wave >> 2;  // 0..1 -> 128 output rows each
  const int wn   = wave & 3;   // 0..3 -> 64 output cols each
  const int qd   = lane >> 4;
  const int l16  = lane & 15;
  const int ro   = l16 & 7;
  const int gc   = (lane & 7) ^ (lane >> 3);

  const short* Ag =
      (const short*)A + (size_t)(tm + wave * 8 + (lane >> 3)) * HIDN + gc * 8;
  const short* Bg =
      (const short*)Bw + (size_t)(tn + (lane >> 3)) * HIDN + gc * 8;

  f32x4 acc[8][4];
#pragma unroll
  for (int i = 0; i < 8; i++)
#pragma unroll
    for (int j = 0; j < 4; j++) acc[i][j] = (f32x4){0.f, 0.f, 0.f, 0.f};
  short8 ar[4][2], br[2][2];
  int cur = 0;

  // prologue: stage tile 0 (order = steady-state issue order), keep the
  // last 4 loads (A23,B23) in flight.
  STAGE_A(0, 0, 0);
  STAGE_B(0, 0, 0);
  STAGE_A(0, 0, 1);
  STAGE_B(0, 0, 1);
  VMW4;
  SBAR;

  for (int t = 0; t < 31; t++) {
    const int nx = cur ^ 1;
    // ---- ph0: quadrant (mh0, nh0); stage A01(t+1)
    LOAD_A(0);
    LOAD_B(0);
    STAGE_A(nx, t + 1, 0);
    SBAR;
    LGKM0;
    MFMA_Q(0, 0);
    VMW4;   // A23(t) landed (issued 2 tiles of phases back); leaves B23(t)+A01(t+1)
    SBAR;
    // ---- ph1: quadrant (mh1, nh0); stage B01(t+1)
    LOAD_A(1);
    STAGE_B(nx, t + 1, 0);
    SBAR;
    LGKM0;
    MFMA_Q(1, 0);
    VMW4;   // B23(t) landed; leaves A01(t+1)+B01(t+1)
    SBAR;
    // ---- ph2: quadrant (mh1, nh1); stage A23(t+1)  (no wait)
    LOAD_B(1);
    STAGE_A(nx, t + 1, 1);
    SBAR;
    LGKM0;
    MFMA_Q(1, 1);
    SBAR;
    // ---- ph3: quadrant (mh0, nh1); stage B23(t+1)
    LOAD_A(0);
    STAGE_B(nx, t + 1, 1);
    SBAR;
    LGKM0;
    MFMA_Q(0, 1);
    VMW4;   // A01(t+1)+B01(t+1) landed; leaves A23(t+1)+B23(t+1)
    SBAR;
    cur = nx;
  }

  // peeled last tile (t = 31): no staging, drain 4 -> 2 -> 0.
  LOAD_A(0);
  LOAD_B(0);
  SBAR;
  LGKM0;
  MFMA_Q(0, 0);
  VMW2;  // A23(31) landed
  SBAR;
  LOAD_A(1);
  LGKM0;
  MFMA_Q(1, 0);
  VMW0;  // B23(31) landed
  SBAR;
  LOAD_B(1);
  LGKM0;
  MFMA_Q(1, 1);
  LOAD_A(0);
  LGKM0;
  MFMA_Q(0, 1);

  // epilogue: acc[i][j] -> row = wm*128 + (i>>2)*64 + (i&3)*16 + qd*4 + r,
  //                       col = wn*64  + (j>>1)*32 + (j&1)*16 + l16
#pragma unroll
  for (int i = 0; i < 8; i++)
#pragma unroll
    for (int j = 0; j < 4; j++)
#pragma unroll
      for (int r = 0; r < 4; r++) {
        const int row = tm + wm * 128 + (i >> 2) * 64 + (i & 3) * 16 + qd * 4 + r;
        const int col = tn + wn * 64 + (j >> 1) * 32 + (j & 1) * 16 + l16;
        float v = acc[i][j][r];
        if (epi == 1) {
          v += bias[col];
          const float ls = fminf(v, 0.f) - log1pf(__expf(-fabsf(v)));
          v = fmaxf(ls * 0.0625f, -50.f);
        }
        if (epi == 2) outf[(size_t)row * HIDN + col] = v;
        else          outb[(size_t)row * HIDN + col] = (bf16_t)v;
      }
}

__global__ __launch_bounds__(512, 2) void k_gemm_proj(
    const bf16_t* __restrict__ Xb,
    const bf16_t* __restrict__ W0, const bf16_t* __restrict__ W1,
    const bf16_t* __restrict__ W2, const bf16_t* __restrict__ W3,
    const bf16_t* __restrict__ W4,
    const float* __restrict__ bg1, const float* __restrict__ bg2,
    bf16_t* __restrict__ Qb, bf16_t* __restrict__ Kb, bf16_t* __restrict__ Vb,
    bf16_t* __restrict__ G1b, bf16_t* __restrict__ G2b) {
  const int z = blockIdx.z;
  const bf16_t* Ws[5] = {W0, W1, W2, W3, W4};
  bf16_t* Os[5] = {Qb, Kb, Vb, G1b, G2b};
  const float* bias = (z == 3) ? bg1 : ((z == 4) ? bg2 : nullptr);
  gemm256(Xb, Ws[z], bias, Os[z], nullptr, (z >= 3) ? 1 : 0);
}

__global__ __launch_bounds__(512, 2) void k_gemm_out(
    const bf16_t* __restrict__ attnB, const bf16_t* __restrict__ Wob,
    float* __restrict__ out) {
  gemm256(attnB, Wob, nullptr, nullptr, out, 2);
}

// ---------------------------------------------------------------------------
__global__ __launch_bounds__(256) void k_cvt_all(
    const float* __restrict__ hid, const float* __restrict__ wq,
    const float* __restrict__ wk, const float* __restrict__ wv,
    const float* __restrict__ wg1, const float* __restrict__ wg2,
    const float* __restrict__ wo, bf16_t* __restrict__ Xb,
    bf16_t* __restrict__ Wd, bf16_t* __restrict__ Wcur,
    bf16_t* __restrict__ WoB) {
  const int y = blockIdx.y;
  const float* srcs[7] = {hid, wq, wk, wv, wg1, wg2, wo};
  bf16_t* dsts[7] = {Xb, Wd, Wd + WELC, Wd + 2 * WELC, Wd + 3 * WELC, Wcur,
                     WoB};
  const int n = (y == 0) ? NELC : WELC;
  const float* src = srcs[y];
  bf16_t* dst = dsts[y];
  const int idx = (blockIdx.x * 256 + threadIdx.x) * 4;
  if (idx < n) {
    const float4 f = *(const float4*)(src + idx);
    dst[idx + 0] = (bf16_t)f.x; dst[idx + 1] = (bf16_t)f.y;
    dst[idx + 2] = (bf16_t)f.z; dst[idx + 3] = (bf16_t)f.w;
  }
}

__global__ __launch_bounds__(256) void k_zero(float* __restrict__ out) {
  out[(size_t)blockIdx.x * 256 + threadIdx.x] = 0.f;
}

// ---------------------------------------------------------------------------
// k_gc: per-chunk inclusive cumsum of gate values along t (fp32 accum),
// stored fp16 IN PLACE over G; chunk totals to Btot (fp32).
// grid (NCHUNK, BB*4, 2), 64 threads. Fully coalesced b128.
// ---------------------------------------------------------------------------
__global__ __launch_bounds__(64) void k_gc(bf16_t* __restrict__ G1b,
                                           bf16_t* __restrict__ G2b,
                                           float* __restrict__ Btot) {
  const int n = blockIdx.x, b = blockIdx.y >> 2, slab = blockIdx.y & 3;
  const int e = blockIdx.z;
  short* P = (short*)(e ? G2b : G1b);
  const int d0 = slab * 512 + threadIdx.x * 8;
  const size_t base = ((size_t)(b * SEQ + n * CHUNK)) * HIDN + d0;
  float c[8] = {0.f, 0.f, 0.f, 0.f, 0.f, 0.f, 0.f, 0.f};
  for (int t = 0; t < CHUNK; t++) {
    short* p = P + base + (size_t)t * HIDN;
    const short8 g = *(const short8*)p;
    short8 o;
#pragma unroll
    for (int j = 0; j < 8; j++) { c[j] += bf2f(g[j]); o[j] = f2hf(c[j]); }
    *(short8*)p = o;
  }
  const int bh = b * 16 + (d0 >> 7);
  float* bp = Btot + ((size_t)(e * NBH + bh) * NCHUNK + n) * DD + (d0 & 127);
#pragma unroll
  for (int j = 0; j < 8; j++) bp[j] = c[j];
}

// ---------------------------------------------------------------------------
// k_sA (per e): fused U-build + intra-chunk output.
//   vT[dv][s](pad66), khatT[dk][s](pad66), k2[s][d](swz), qh[t][d](swz),
//   Ps[t][s](pad72).  U = vT x khatT -> UT global (chunk-swizzled rows).
//   P = qh x k2 (causal), o_intra = Ps x vT -> attn (w_e folded).
// ---------------------------------------------------------------------------
template <int ACC>
__global__ __launch_bounds__(256) void k_sA(
    const bf16_t* __restrict__ Qb, const bf16_t* __restrict__ Kb,
    const bf16_t* __restrict__ Vb, const bf16_t* __restrict__ Gc,
    bf16_t* __restrict__ UT, const float* __restrict__ alpha,
    bf16_t* __restrict__ attn) {
  const int n = blockIdx.x, bh = blockIdx.y;
  const int b = bh >> 4, h = bh & 15;
  const size_t rbase = ((size_t)(b * SEQ + n * CHUNK)) * HIDN + h * DD;
  const int tid = threadIdx.x;
  const int wave = tid >> 6, lane = tid & 63, qd = lane >> 4, l16 = lane & 15;
  __shared__ short vT[128 * 66];
  __shared__ short k2s[64 * 128];
  __shared__ short r3[128 * 66];  // khatT, then reused as qh (64*128 prefix)
  __shared__ short Ps[64 * 72];
  const float mx = fmaxf(alpha[0], alpha[1]);
  const float x0 = __expf(alpha[0] - mx), x1 = __expf(alpha[1] - mx);
  const float wsc = ((ACC ? x1 : x0) / (x0 + x1)) * QSCALE;

  const short* Kp = (const short*)Kb;
  const short* Vp = (const short*)Vb;
  const short* Gp = (const short*)Gc;
  const short* Qp = (const short*)Qb;

  // builds: vT (col-writes, bank d mod 32), k2 (swz b128), khatT (col-writes)
#pragma unroll
  for (int rep = 0; rep < 4; rep++) {
    const int slot = rep * 256 + tid;
    const int t = slot >> 4, ch = slot & 15;
    const size_t ga = rbase + (size_t)t * HIDN + ch * 8;
    const short8 vv = *(const short8*)(Vp + ga);
    const short8 kk = *(const short8*)(Kp + ga);
    const short8 cc = *(const short8*)(Gp + ga);
    const short8 c6 = *(const short8*)(Gp + rbase + (size_t)63 * HIDN + ch * 8);
    short8 k2v;
#pragma unroll
    for (int j = 0; j < 8; j++) {
      const int d = ch * 8 + j;
      vT[d * 66 + t] = vv[j];
      const float c = hf2f(cc[j]);
      const float kf = bf2f(kk[j]);
      k2v[j] = f2bf(kf * __expf(-c));
      r3[d * 66 + t] = f2bf(kf * __expf(hf2f(c6[j]) - c));
    }
    *(short8*)&k2s[t * 128 + ((ch ^ (t & 7)) << 3)] = k2v;
  }
  __syncthreads();

  {  // U-MFMA: C[dv][dk] = sum_s vT[dv][s] * khatT[dk][s]
    const int m0 = (wave >> 1) * 64, n0 = (wave & 1) * 64;
    const int* vTi = (const int*)vT;
    const int* r3i = (const int*)r3;
    f32x4 uacc[4][4];
#pragma unroll
    for (int i = 0; i < 4; i++)
#pragma unroll
      for (int j = 0; j < 4; j++) uacc[i][j] = (f32x4){0.f, 0.f, 0.f, 0.f};
#pragma unroll
    for (int ks = 0; ks < 2; ks++) {
      const int ch = ks * 4 + qd;
      short8 af[4], bfv[4];
#pragma unroll
      for (int i = 0; i < 4; i++) {
        const int dv = m0 + i * 16 + l16;
        const int ba = dv * 33 + ch * 4;
#pragma unroll
        for (int w2 = 0; w2 < 4; w2++) {
          const int v = vTi[ba + w2];
          af[i][2 * w2] = (short)(v & 0xffff);
          af[i][2 * w2 + 1] = (short)((unsigned)v >> 16);
        }
      }
#pragma unroll
      for (int j = 0; j < 4; j++) {
        const int dk = n0 + j * 16 + l16;
        const int ba = dk * 33 + ch * 4;
#pragma unroll
        for (int w2 = 0; w2 < 4; w2++) {
          const int v = r3i[ba + w2];
          bfv[j][2 * w2] = (short)(v & 0xffff);
          bfv[j][2 * w2 + 1] = (short)((unsigned)v >> 16);
        }
      }
#pragma unroll
      for (int i = 0; i < 4; i++)
#pragma unroll
        for (int j = 0; j < 4; j++)
          uacc[i][j] = __builtin_amdgcn_mfma_f32_16x16x32_bf16(
              af[i], bfv[j], uacc[i][j], 0, 0, 0);
    }
    short* Uo = (short*)UT + (size_t)(bh * NCHUNK + n) * (DD * DD);
#pragma unroll
    for (int i = 0; i < 4; i++)
#pragma unroll
      for (int j = 0; j < 4; j++)
#pragma unroll
        for (int r = 0; r < 4; r++) {
          const int dv = m0 + i * 16 + qd * 4 + r;
          const int dk = n0 + j * 16 + l16;
          Uo[dv * 128 + (((dk >> 3) ^ (dv & 7)) << 3) + (dk & 7)] =
              f2bf(uacc[i][j][r]);
        }
  }
  __syncthreads();

  // qh build (overwrites khatT region)
#pragma unroll
  for (int rep = 0; rep < 4; rep++) {
    const int slot = rep * 256 + tid;
    const int t = slot >> 4, ch = slot & 15;
    const size_t ga = rbase + (size_t)t * HIDN + ch * 8;
    const short8 qq = *(const short8*)(Qp + ga);
    const short8 cc = *(const short8*)(Gp + ga);
    short8 o;
#pragma unroll
    for (int j = 0; j < 8; j++)
      o[j] = f2bf(bf2f(qq[j]) * wsc * __expf(hf2f(cc[j])));
    *(short8*)&r3[t * 128 + ((ch ^ (t & 7)) << 3)] = o;
  }
  __syncthreads();

  {  // P = qh x k2 (causal): wave owns t-rows [wave*16, +16)
    f32x4 pacc[4];
#pragma unroll
    for (int j = 0; j < 4; j++) pacc[j] = (f32x4){0.f, 0.f, 0.f, 0.f};
    const int tq = wave * 16 + l16;
#pragma unroll
    for (int ks = 0; ks < 4; ks++) {
      const int ch = ks * 4 + qd;
      const short8 a = *(const short8*)&r3[tq * 128 + ((ch ^ (tq & 7)) << 3)];
#pragma unroll
      for (int j = 0; j < 4; j++) {
        const int s = j * 16 + l16;
        const short8 bq =
            *(const short8*)&k2s[s * 128 + ((ch ^ (s & 7)) << 3)];
        pacc[j] =
            __builtin_amdgcn_mfma_f32_16x16x32_bf16(a, bq, pacc[j], 0, 0, 0);
      }
    }
#pragma unroll
    for (int j = 0; j < 4; j++)
#pragma unroll
      for (int r = 0; r < 4; r++) {
        const int t = wave * 16 + qd * 4 + r, s = j * 16 + l16;
        Ps[t * 72 + s] = (t >= s) ? f2bf(pacc[j][r]) : (short)0;
      }
  }
  __syncthreads();

  // o_intra = Ps x vT
  f32x4 oacc[8];
#pragma unroll
  for (int j = 0; j < 8; j++) oacc[j] = (f32x4){0.f, 0.f, 0.f, 0.f};
  {
    const int* vTi = (const int*)vT;
    const int tq = wave * 16 + l16;
#pragma unroll
    for (int ks = 0; ks < 2; ks++) {
      const int ch = ks * 4 + qd;
      const short8 a = *(const short8*)&Ps[tq * 72 + ch * 8];
#pragma unroll
      for (int j = 0; j < 8; j++) {
        const int dv = j * 16 + l16;
        const int ba = dv * 33 + ch * 4;
        short8 bq;
#pragma unroll
        for (int w2 = 0; w2 < 4; w2++) {
          const int v = vTi[ba + w2];
          bq[2 * w2] = (short)(v & 0xffff);
          bq[2 * w2 + 1] = (short)((unsigned)v >> 16);
        }
        oacc[j] =
            __builtin_amdgcn_mfma_f32_16x16x32_bf16(a, bq, oacc[j], 0, 0, 0);
      }
    }
  }
#pragma unroll
  for (int j = 0; j < 8; j++)
#pragma unroll
    for (int r = 0; r < 4; r++) {
      const int t = wave * 16 + qd * 4 + r;
      const int dv = j * 16 + l16;
      bf16_t* p = &attn[rbase + (size_t)t * HIDN + dv];
      if (ACC) *p = (bf16_t)((float)*p + oacc[j][r]);
      else     *p = (bf16_t)oacc[j][r];
    }
}

// ---------------------------------------------------------------------------
// k_s2: sequential chunk combine (swizzled UT rows); S^T in place.
// ---------------------------------------------------------------------------
__global__ __launch_bounds__(256) void k_s2(bf16_t* __restrict__ UT,
                                            const float* __restrict__ Btot) {
  const int dg = blockIdx.x, bh = blockIdx.y;
  const int dv = dg * 8 + (threadIdx.x >> 5);
  const int dk0 = (threadIdx.x & 31) * 4;
  const int pos = dv * 128 + (((dk0 >> 3) ^ (dv & 7)) << 3) + (dk0 & 7);
  float st[4] = {0.f, 0.f, 0.f, 0.f};
  for (int nn = 0; nn < NCHUNK; nn++) {
    short* p = (short*)UT + (size_t)(bh * NCHUNK + nn) * (DD * DD) + pos;
    const float4 bp =
        *(const float4*)(Btot + (size_t)(bh * NCHUNK + nn) * DD + dk0);
    short u0 = p[0], u1 = p[1], u2 = p[2], u3 = p[3];
    p[0] = f2bf(st[0]); p[1] = f2bf(st[1]);
    p[2] = f2bf(st[2]); p[3] = f2bf(st[3]);
    st[0] = st[0] * __expf(bp.x) + bf2f(u0);
    st[1] = st[1] * __expf(bp.y) + bf2f(u1);
    st[2] = st[2] * __expf(bp.z) + bf2f(u2);
    st[3] = st[3] * __expf(bp.w) + bf2f(u3);
  }
}

// ---------------------------------------------------------------------------
// k_s3b: inter-chunk  attn += qh @ S.  S staged via gload16 (async, overlaps
// qh rebuild); both read as swizzled b128 frags.
// ---------------------------------------------------------------------------
__global__ __launch_bounds__(256) void k_s3b(
    const bf16_t* __restrict__ Qb, const bf16_t* __restrict__ Gc,
    const bf16_t* __restrict__ UT, const float* __restrict__ alpha,
    const int e, bf16_t* __restrict__ attn) {
  const int n = blockIdx.x, bh = blockIdx.y;
  const int b = bh >> 4, h = bh & 15;
  const size_t rbase = ((size_t)(b * SEQ + n * CHUNK)) * HIDN + h * DD;
  const int tid = threadIdx.x;
  const int wave = tid >> 6, lane = tid & 63, qd = lane >> 4, l16 = lane & 15;
  __shared__ short qh[64 * 128];
  __shared__ short Ss[128 * 128];
  const float mx = fmaxf(alpha[0], alpha[1]);
  const float x0 = __expf(alpha[0] - mx), x1 = __expf(alpha[1] - mx);
  const float wsc = ((e ? x1 : x0) / (x0 + x1)) * QSCALE;

  // async-stage S tile (2048 x 16B chunks, lane-linear, layout preserved)
  const short* Sp = (const short*)UT + (size_t)(bh * NCHUNK + n) * (DD * DD);
#pragma unroll
  for (int rep = 0; rep < 8; rep++) {
    const int c = rep * 256 + tid;
    gload_lds16(Sp + c * 8, &Ss[c * 8]);
  }
  // qh rebuild (overlaps the async loads)
  const short* Qp = (const short*)Qb;
  const short* Gp = (const short*)Gc;
#pragma unroll
  for (int rep = 0; rep < 4; rep++) {
    const int slot = rep * 256 + tid;
    const int t = slot >> 4, ch = slot & 15;
    const size_t ga = rbase + (size_t)t * HIDN + ch * 8;
    const short8 qq = *(const short8*)(Qp + ga);
    const short8 cc = *(const short8*)(Gp + ga);
    short8 o;
#pragma unroll
    for (int j = 0; j < 8; j++)
      o[j] = f2bf(bf2f(qq[j]) * wsc * __expf(hf2f(cc[j])));
    *(short8*)&qh[t * 128 + ((ch ^ (t & 7)) << 3)] = o;
  }
  __syncthreads();

  f32x4 oacc[8];
#pragma unroll
  for (int j = 0; j < 8; j++) oacc[j] = (f32x4){0.f, 0.f, 0.f, 0.f};
  const int tq = wave * 16 + l16;
#pragma unroll
  for (int ks = 0; ks < 4; ks++) {
    const int ch = ks * 4 + qd;
    const short8 a = *(const short8*)&qh[tq * 128 + ((ch ^ (tq & 7)) << 3)];
#pragma unroll
    for (int j = 0; j < 8; j++) {
      const int dv = j * 16 + l16;
      const short8 bq = *(const short8*)&Ss[dv * 128 + ((ch ^ (dv & 7)) << 3)];
      oacc[j] =
          __builtin_amdgcn_mfma_f32_16x16x32_bf16(a, bq, oacc[j], 0, 0, 0);
    }
  }
#pragma unroll
  for (int j = 0; j < 8; j++)
#pragma unroll
    for (int r = 0; r < 4; r++) {
      const int t = wave * 16 + qd * 4 + r;
      const int dv = j * 16 + l16;
      bf16_t* p = &attn[rbase + (size_t)t * HIDN + dv];
      *p = (bf16_t)((float)*p + oacc[j][r]);
    }
}

// ---------------------------------------------------------------------------
extern "C" void kernel_launch(void* const* d_in, const int* in_sizes, int n_in,
                              void* d_out, int out_size, void* d_ws,
                              size_t ws_size, hipStream_t stream) {
  const float* hid  = (const float*)d_in[0];
  const float* wq   = (const float*)d_in[1];
  const float* wk   = (const float*)d_in[2];
  const float* wv   = (const float*)d_in[3];
  const float* wo   = (const float*)d_in[4];
  const float* wg1  = (const float*)d_in[5];
  const float* bg1  = (const float*)d_in[6];
  const float* wg2  = (const float*)d_in[7];
  const float* bg2  = (const float*)d_in[8];
  const float* alph = (const float*)d_in[9];
  float* out = (float*)d_out;
  (void)in_sizes; (void)n_in; (void)out_size;

  char* ws = (char*)d_ws;
  size_t off = 0;
  auto alloc = [&](size_t bytes) -> void* {
    void* p = ws + off;
    off += (bytes + 255) & ~(size_t)255;
    return p;
  };
  const size_t NEL = NELC, WEL = WELC;
  bf16_t* Xb   = (bf16_t*)alloc(NEL * 2);  // X; reused as attn
  bf16_t* Wcur = (bf16_t*)alloc(WEL * 2);  // Wg2
  bf16_t* WoB  = (bf16_t*)alloc(WEL * 2);  // Wo
  bf16_t* Qb   = (bf16_t*)alloc(NEL * 2);
  bf16_t* Kb   = (bf16_t*)alloc(NEL * 2);
  bf16_t* Vb   = (bf16_t*)alloc(NEL * 2);
  bf16_t* G1b  = (bf16_t*)alloc(NEL * 2);
  bf16_t* G2b  = (bf16_t*)alloc(NEL * 2);
  float*  Btot = (float*) alloc((size_t)2 * NBH * NCHUNK * DD * 4);
  bf16_t* Wd = (bf16_t*)d_out;  // weights, then U/S states, then final out
  bf16_t* UT = (bf16_t*)d_out;

  if (off > ws_size) {  // diagnostic fallback
    k_zero<<<dim3((unsigned)(NEL / 256)), 256, 0, stream>>>(out);
    return;
  }

  k_cvt_all<<<dim3(8192, 7), 256, 0, stream>>>(hid, wq, wk, wv, wg1, wg2, wo,
                                               Xb, Wd, Wcur, WoB);
  k_gemm_proj<<<dim3(16, 8, 5), 512, 0, stream>>>(
      Xb, Wd, Wd + WEL, Wd + 2 * WEL, Wd + 3 * WEL, Wcur, bg1, bg2, Qb, Kb, Vb,
      G1b, G2b);
  k_gc<<<dim3(NCHUNK, BB * 4, 2), 64, 0, stream>>>(G1b, G2b, Btot);

  const dim3 gs(NCHUNK, NBH), g2(16, NBH);
  const size_t BSTRIDE = (size_t)NBH * NCHUNK * DD;
  // e = 0
  k_sA<0><<<gs, 256, 0, stream>>>(Qb, Kb, Vb, G1b, UT, alph, Xb);
  k_s2<<<g2, 256, 0, stream>>>(UT, Btot);
  k_s3b<<<gs, 256, 0, stream>>>(Qb, G1b, UT, alph, 0, Xb);
  // e = 1
  k_sA<1><<<gs, 256, 0, stream>>>(Qb, Kb, Vb, G2b, UT, alph, Xb);
  k_s2<<<g2, 256, 0, stream>>>(UT, Btot + BSTRIDE);
  k_s3b<<<gs, 256, 0, stream>>>(Qb, G2b, UT, alph, 1, Xb);

  k_gemm_out<<<dim3(16, 8), 512, 0, stream>>>(Xb, WoB, out);
}

// Round 2
// 580.988 us; speedup vs baseline: 1.1433x; 1.1433x over previous
//
#include <hip/hip_runtime.h>
#include <cstdint>
#include <cstddef>

// ============================================================================
// DualStateLinearAttention on MI355X — round 7
//  R6 post-mortem: 256^2 tile -> 640 blocks on 512 slots = 62.5% slot util;
//  steady-state DID improve (~890 TF) but tail ate it. R7: BM=256 BN=128,
//  grid 16x16x5 = 1280 blocks = exactly 5 rounds of 256 CUs (zero tail),
//  triple-buffered LDS (144KB), stage 2 K-tiles ahead, ONE counted vmcnt(6)
//  per K-tile (~3 phases deep), 2 phases/K-tile x 16 MFMA, setprio kept.
// Pipeline: cvt -> proj(5x fused) -> gc -> [sA -> s2 -> s3b] x2 -> out-GEMM.
// ============================================================================

#define BB     2
#define SEQ    2048
#define HIDN   2048
#define NH     16
#define DD     128
#define CHUNK  64
#define NCHUNK (SEQ / CHUNK)   // 32
#define NBH    (BB * NH)       // 32
#define NELC   8388608
#define WELC   4194304
static constexpr float QSCALE = 0.08838834764831845f;  // 128^-0.5

typedef __bf16 bf16_t;
typedef _Float16 half_t;
typedef short  short8 __attribute__((ext_vector_type(8)));
typedef float  f32x4  __attribute__((ext_vector_type(4)));

__device__ __forceinline__ float bf2f(short u) {
  return (float)__builtin_bit_cast(bf16_t, u);
}
__device__ __forceinline__ short f2bf(float f) {
  return __builtin_bit_cast(short, (bf16_t)f);
}
__device__ __forceinline__ float hf2f(short u) {
  return (float)__builtin_bit_cast(half_t, u);
}
__device__ __forceinline__ short f2hf(float f) {
  return __builtin_bit_cast(short, (half_t)f);
}

__device__ __forceinline__ void gload_lds16(const void* g, void* l) {
  __builtin_amdgcn_global_load_lds(
      (__attribute__((address_space(1))) unsigned int*)g,
      (__attribute__((address_space(3))) unsigned int*)l, 16, 0, 0);
}

#define VMW6 asm volatile("s_waitcnt vmcnt(6)" ::: "memory")
#define VMW0 asm volatile("s_waitcnt vmcnt(0)" ::: "memory")
#define LGKM0 asm volatile("s_waitcnt lgkmcnt(0)" ::: "memory")
#define SBAR __builtin_amdgcn_s_barrier()

// ---------------------------------------------------------------------------
// 256x128 bf16 MFMA GEMM, BK=64, triple-buffered LDS, 2 phases/K-tile,
// stage 2 tiles ahead, single vmcnt(6)/K-tile. Gather swizzle:
// LDS[r][chunk c] = G[r][chunk c^(r&7)] (involution; stage+read both sides).
// ---------------------------------------------------------------------------

// A tile rows: pair0 = {0-63, 128-191}, pair1 = {64-127, 192-255} (2 loads)
#define STG_A(buf, kt, pair)                                                \
  {                                                                         \
    const size_t ko = (size_t)(kt) * 64;                                    \
    gload_lds16(Ag + (size_t)((pair) * 64) * HIDN + ko,                     \
                (void*)&As[buf][((pair) * 64 + wave * 8) * 64]);            \
    gload_lds16(Ag + (size_t)((pair) * 64 + 128) * HIDN + ko,               \
                (void*)&As[buf][((pair) * 64 + 128 + wave * 8) * 64]);      \
  }

// B tile rows(=out cols): half h = rows [h*64, +64) (1 load)
#define STG_B(buf, kt, half)                                                \
  {                                                                         \
    gload_lds16(Bg + (size_t)((half) * 64) * HIDN + (size_t)(kt) * 64,      \
                (void*)&Bs[buf][((half) * 64 + wave * 8) * 64]);            \
  }

#define LDA_PH(mh, rb)                                                      \
  {                                                                         \
    _Pragma("unroll") for (int f = 0; f < 4; f++) {                         \
      const int row = wm * 128 + (mh) * 64 + f * 16 + l16;                  \
      ar[f][0] = *(const short8*)&As[rb][row * 64 + ((qd ^ ro) << 3)];      \
      ar[f][1] =                                                            \
          *(const short8*)&As[rb][row * 64 + (((4 + qd) ^ ro) << 3)];       \
    }                                                                       \
  }

#define LDB_PH(rb)                                                          \
  {                                                                         \
    _Pragma("unroll") for (int g = 0; g < 2; g++) {                         \
      const int col = wn * 32 + g * 16 + l16;                               \
      br[g][0] = *(const short8*)&Bs[rb][col * 64 + ((qd ^ ro) << 3)];      \
      br[g][1] =                                                            \
          *(const short8*)&Bs[rb][col * 64 + (((4 + qd) ^ ro) << 3)];       \
    }                                                                       \
  }

#define MFMA_PH(mh)                                                         \
  {                                                                         \
    __builtin_amdgcn_s_setprio(1);                                          \
    _Pragma("unroll") for (int ks = 0; ks < 2; ks++)                        \
    _Pragma("unroll") for (int f = 0; f < 4; f++)                           \
    _Pragma("unroll") for (int g = 0; g < 2; g++)                           \
      acc[(mh) * 4 + f][g] = __builtin_amdgcn_mfma_f32_16x16x32_bf16(       \
          ar[f][ks], br[g][ks], acc[(mh) * 4 + f][g], 0, 0, 0);             \
    __builtin_amdgcn_s_setprio(0);                                          \
  }

__device__ __forceinline__ void gemm256(const bf16_t* __restrict__ A,
                                        const bf16_t* __restrict__ Bw,
                                        const float*  __restrict__ bias,
                                        bf16_t* __restrict__ outb,
                                        float*  __restrict__ outf, int epi) {
  __shared__ short As[3][256 * 64];  // 96 KB
  __shared__ short Bs[3][128 * 64];  // 48 KB
  const int tm   = blockIdx.x * 256;
  const int tn   = blockIdx.y * 128;
  const int tid  = threadIdx.x;
  const int wave = tid >> 6;
  const int lane = tid & 63;
  const int wm   = wave >> 2;  // 0..1 -> 128 output rows each
  const int wn   = wave & 3;   // 0..3 -> 32 output cols each
  const int qd   = lane >> 4;
  const int l16  = lane & 15;
  const int ro   = l16 & 7;
  const int gc   = (lane & 7) ^ (lane >> 3);

  const short* Ag =
      (const short*)A + (size_t)(tm + wave * 8 + (lane >> 3)) * HIDN + gc * 8;
  const short* Bg =
      (const short*)Bw + (size_t)(tn + wave * 8 + (lane >> 3)) * HIDN + gc * 8;

  f32x4 acc[8][2];
#pragma unroll
  for (int i = 0; i < 8; i++)
#pragma unroll
    for (int j = 0; j < 2; j++) acc[i][j] = (f32x4){0.f, 0.f, 0.f, 0.f};
  short8 ar[4][2], br[2][2];

  // prologue: stage K-tiles 0 and 1 (6 loads each); drain tile 0 only.
  STG_A(0, 0, 0); STG_B(0, 0, 0); STG_B(0, 0, 1); STG_A(0, 0, 1);
  STG_A(1, 1, 0); STG_B(1, 1, 0); STG_B(1, 1, 1); STG_A(1, 1, 1);
  VMW6;
  SBAR;

  int rd = 0, st = 2;
  for (int t = 0; t < 32; t++) {
    // ---- ph0: quadrant mh=0; stage A-pair0 + B-half0 of tile t+2
    LDA_PH(0, rd);
    LDB_PH(rd);
    if (t < 30) { STG_A(st, t + 2, 0); STG_B(st, t + 2, 0); }
    SBAR;
    LGKM0;
    MFMA_PH(0);
    SBAR;
    // ---- ph1: quadrant mh=1; stage B-half1 + A-pair1 of tile t+2
    LDA_PH(1, rd);
    if (t < 30) { STG_B(st, t + 2, 1); STG_A(st, t + 2, 1); }
    SBAR;
    LGKM0;
    MFMA_PH(1);
    if (t < 30) { VMW6; }          // drains tile t+1's 6 loads (issued t-1)
    else if (t == 30) { VMW0; }    // drains tile 31
    SBAR;
    rd = (rd == 2) ? 0 : rd + 1;
    st = (st == 2) ? 0 : st + 1;
  }

  // epilogue: row = wm*128 + (i>>2)*64 + (i&3)*16 + qd*4 + r
  //           col = wn*32 + j*16 + l16
#pragma unroll
  for (int i = 0; i < 8; i++)
#pragma unroll
    for (int j = 0; j < 2; j++)
#pragma unroll
      for (int r = 0; r < 4; r++) {
        const int row =
            tm + wm * 128 + (i >> 2) * 64 + (i & 3) * 16 + qd * 4 + r;
        const int col = tn + wn * 32 + j * 16 + l16;
        float v = acc[i][j][r];
        if (epi == 1) {
          v += bias[col];
          const float ls = fminf(v, 0.f) - log1pf(__expf(-fabsf(v)));
          v = fmaxf(ls * 0.0625f, -50.f);
        }
        if (epi == 2) outf[(size_t)row * HIDN + col] = v;
        else          outb[(size_t)row * HIDN + col] = (bf16_t)v;
      }
}

__global__ __launch_bounds__(512, 2) void k_gemm_proj(
    const bf16_t* __restrict__ Xb,
    const bf16_t* __restrict__ W0, const bf16_t* __restrict__ W1,
    const bf16_t* __restrict__ W2, const bf16_t* __restrict__ W3,
    const bf16_t* __restrict__ W4,
    const float* __restrict__ bg1, const float* __restrict__ bg2,
    bf16_t* __restrict__ Qb, bf16_t* __restrict__ Kb, bf16_t* __restrict__ Vb,
    bf16_t* __restrict__ G1b, bf16_t* __restrict__ G2b) {
  const int z = blockIdx.z;
  const bf16_t* Ws[5] = {W0, W1, W2, W3, W4};
  bf16_t* Os[5] = {Qb, Kb, Vb, G1b, G2b};
  const float* bias = (z == 3) ? bg1 : ((z == 4) ? bg2 : nullptr);
  gemm256(Xb, Ws[z], bias, Os[z], nullptr, (z >= 3) ? 1 : 0);
}

__global__ __launch_bounds__(512, 2) void k_gemm_out(
    const bf16_t* __restrict__ attnB, const bf16_t* __restrict__ Wob,
    float* __restrict__ out) {
  gemm256(attnB, Wob, nullptr, nullptr, out, 2);
}

// ---------------------------------------------------------------------------
__global__ __launch_bounds__(256) void k_cvt_all(
    const float* __restrict__ hid, const float* __restrict__ wq,
    const float* __restrict__ wk, const float* __restrict__ wv,
    const float* __restrict__ wg1, const float* __restrict__ wg2,
    const float* __restrict__ wo, bf16_t* __restrict__ Xb,
    bf16_t* __restrict__ Wd, bf16_t* __restrict__ Wcur,
    bf16_t* __restrict__ WoB) {
  const int y = blockIdx.y;
  const float* srcs[7] = {hid, wq, wk, wv, wg1, wg2, wo};
  bf16_t* dsts[7] = {Xb, Wd, Wd + WELC, Wd + 2 * WELC, Wd + 3 * WELC, Wcur,
                     WoB};
  const int n = (y == 0) ? NELC : WELC;
  const float* src = srcs[y];
  bf16_t* dst = dsts[y];
  const int idx = (blockIdx.x * 256 + threadIdx.x) * 4;
  if (idx < n) {
    const float4 f = *(const float4*)(src + idx);
    dst[idx + 0] = (bf16_t)f.x; dst[idx + 1] = (bf16_t)f.y;
    dst[idx + 2] = (bf16_t)f.z; dst[idx + 3] = (bf16_t)f.w;
  }
}

__global__ __launch_bounds__(256) void k_zero(float* __restrict__ out) {
  out[(size_t)blockIdx.x * 256 + threadIdx.x] = 0.f;
}

// ---------------------------------------------------------------------------
// k_gc: per-chunk inclusive cumsum of gate values along t (fp32 accum),
// stored fp16 IN PLACE over G; chunk totals to Btot (fp32).
// grid (NCHUNK, BB*4, 2), 64 threads. Fully coalesced b128.
// ---------------------------------------------------------------------------
__global__ __launch_bounds__(64) void k_gc(bf16_t* __restrict__ G1b,
                                           bf16_t* __restrict__ G2b,
                                           float* __restrict__ Btot) {
  const int n = blockIdx.x, b = blockIdx.y >> 2, slab = blockIdx.y & 3;
  const int e = blockIdx.z;
  short* P = (short*)(e ? G2b : G1b);
  const int d0 = slab * 512 + threadIdx.x * 8;
  const size_t base = ((size_t)(b * SEQ + n * CHUNK)) * HIDN + d0;
  float c[8] = {0.f, 0.f, 0.f, 0.f, 0.f, 0.f, 0.f, 0.f};
  for (int t = 0; t < CHUNK; t++) {
    short* p = P + base + (size_t)t * HIDN;
    const short8 g = *(const short8*)p;
    short8 o;
#pragma unroll
    for (int j = 0; j < 8; j++) { c[j] += bf2f(g[j]); o[j] = f2hf(c[j]); }
    *(short8*)p = o;
  }
  const int bh = b * 16 + (d0 >> 7);
  float* bp = Btot + ((size_t)(e * NBH + bh) * NCHUNK + n) * DD + (d0 & 127);
#pragma unroll
  for (int j = 0; j < 8; j++) bp[j] = c[j];
}

// ---------------------------------------------------------------------------
// k_sA (per e): fused U-build + intra-chunk output.
//   vT[dv][s](pad66), khatT[dk][s](pad66), k2[s][d](swz), qh[t][d](swz),
//   Ps[t][s](pad72).  U = vT x khatT -> UT global (chunk-swizzled rows).
//   P = qh x k2 (causal), o_intra = Ps x vT -> attn (w_e folded).
// ---------------------------------------------------------------------------
template <int ACC>
__global__ __launch_bounds__(256) void k_sA(
    const bf16_t* __restrict__ Qb, const bf16_t* __restrict__ Kb,
    const bf16_t* __restrict__ Vb, const bf16_t* __restrict__ Gc,
    bf16_t* __restrict__ UT, const float* __restrict__ alpha,
    bf16_t* __restrict__ attn) {
  const int n = blockIdx.x, bh = blockIdx.y;
  const int b = bh >> 4, h = bh & 15;
  const size_t rbase = ((size_t)(b * SEQ + n * CHUNK)) * HIDN + h * DD;
  const int tid = threadIdx.x;
  const int wave = tid >> 6, lane = tid & 63, qd = lane >> 4, l16 = lane & 15;
  __shared__ short vT[128 * 66];
  __shared__ short k2s[64 * 128];
  __shared__ short r3[128 * 66];  // khatT, then reused as qh (64*128 prefix)
  __shared__ short Ps[64 * 72];
  const float mx = fmaxf(alpha[0], alpha[1]);
  const float x0 = __expf(alpha[0] - mx), x1 = __expf(alpha[1] - mx);
  const float wsc = ((ACC ? x1 : x0) / (x0 + x1)) * QSCALE;

  const short* Kp = (const short*)Kb;
  const short* Vp = (const short*)Vb;
  const short* Gp = (const short*)Gc;
  const short* Qp = (const short*)Qb;

  // builds: vT (col-writes, bank d mod 32), k2 (swz b128), khatT (col-writes)
#pragma unroll
  for (int rep = 0; rep < 4; rep++) {
    const int slot = rep * 256 + tid;
    const int t = slot >> 4, ch = slot & 15;
    const size_t ga = rbase + (size_t)t * HIDN + ch * 8;
    const short8 vv = *(const short8*)(Vp + ga);
    const short8 kk = *(const short8*)(Kp + ga);
    const short8 cc = *(const short8*)(Gp + ga);
    const short8 c6 = *(const short8*)(Gp + rbase + (size_t)63 * HIDN + ch * 8);
    short8 k2v;
#pragma unroll
    for (int j = 0; j < 8; j++) {
      const int d = ch * 8 + j;
      vT[d * 66 + t] = vv[j];
      const float c = hf2f(cc[j]);
      const float kf = bf2f(kk[j]);
      k2v[j] = f2bf(kf * __expf(-c));
      r3[d * 66 + t] = f2bf(kf * __expf(hf2f(c6[j]) - c));
    }
    *(short8*)&k2s[t * 128 + ((ch ^ (t & 7)) << 3)] = k2v;
  }
  __syncthreads();

  {  // U-MFMA: C[dv][dk] = sum_s vT[dv][s] * khatT[dk][s]
    const int m0 = (wave >> 1) * 64, n0 = (wave & 1) * 64;
    const int* vTi = (const int*)vT;
    const int* r3i = (const int*)r3;
    f32x4 uacc[4][4];
#pragma unroll
    for (int i = 0; i < 4; i++)
#pragma unroll
      for (int j = 0; j < 4; j++) uacc[i][j] = (f32x4){0.f, 0.f, 0.f, 0.f};
#pragma unroll
    for (int ks = 0; ks < 2; ks++) {
      const int ch = ks * 4 + qd;
      short8 af[4], bfv[4];
#pragma unroll
      for (int i = 0; i < 4; i++) {
        const int dv = m0 + i * 16 + l16;
        const int ba = dv * 33 + ch * 4;
#pragma unroll
        for (int w2 = 0; w2 < 4; w2++) {
          const int v = vTi[ba + w2];
          af[i][2 * w2] = (short)(v & 0xffff);
          af[i][2 * w2 + 1] = (short)((unsigned)v >> 16);
        }
      }
#pragma unroll
      for (int j = 0; j < 4; j++) {
        const int dk = n0 + j * 16 + l16;
        const int ba = dk * 33 + ch * 4;
#pragma unroll
        for (int w2 = 0; w2 < 4; w2++) {
          const int v = r3i[ba + w2];
          bfv[j][2 * w2] = (short)(v & 0xffff);
          bfv[j][2 * w2 + 1] = (short)((unsigned)v >> 16);
        }
      }
#pragma unroll
      for (int i = 0; i < 4; i++)
#pragma unroll
        for (int j = 0; j < 4; j++)
          uacc[i][j] = __builtin_amdgcn_mfma_f32_16x16x32_bf16(
              af[i], bfv[j], uacc[i][j], 0, 0, 0);
    }
    short* Uo = (short*)UT + (size_t)(bh * NCHUNK + n) * (DD * DD);
#pragma unroll
    for (int i = 0; i < 4; i++)
#pragma unroll
      for (int j = 0; j < 4; j++)
#pragma unroll
        for (int r = 0; r < 4; r++) {
          const int dv = m0 + i * 16 + qd * 4 + r;
          const int dk = n0 + j * 16 + l16;
          Uo[dv * 128 + (((dk >> 3) ^ (dv & 7)) << 3) + (dk & 7)] =
              f2bf(uacc[i][j][r]);
        }
  }
  __syncthreads();

  // qh build (overwrites khatT region)
#pragma unroll
  for (int rep = 0; rep < 4; rep++) {
    const int slot = rep * 256 + tid;
    const int t = slot >> 4, ch = slot & 15;
    const size_t ga = rbase + (size_t)t * HIDN + ch * 8;
    const short8 qq = *(const short8*)(Qp + ga);
    const short8 cc = *(const short8*)(Gp + ga);
    short8 o;
#pragma unroll
    for (int j = 0; j < 8; j++)
      o[j] = f2bf(bf2f(qq[j]) * wsc * __expf(hf2f(cc[j])));
    *(short8*)&r3[t * 128 + ((ch ^ (t & 7)) << 3)] = o;
  }
  __syncthreads();

  {  // P = qh x k2 (causal): wave owns t-rows [wave*16, +16)
    f32x4 pacc[4];
#pragma unroll
    for (int j = 0; j < 4; j++) pacc[j] = (f32x4){0.f, 0.f, 0.f, 0.f};
    const int tq = wave * 16 + l16;
#pragma unroll
    for (int ks = 0; ks < 4; ks++) {
      const int ch = ks * 4 + qd;
      const short8 a = *(const short8*)&r3[tq * 128 + ((ch ^ (tq & 7)) << 3)];
#pragma unroll
      for (int j = 0; j < 4; j++) {
        const int s = j * 16 + l16;
        const short8 bq =
            *(const short8*)&k2s[s * 128 + ((ch ^ (s & 7)) << 3)];
        pacc[j] =
            __builtin_amdgcn_mfma_f32_16x16x32_bf16(a, bq, pacc[j], 0, 0, 0);
      }
    }
#pragma unroll
    for (int j = 0; j < 4; j++)
#pragma unroll
      for (int r = 0; r < 4; r++) {
        const int t = wave * 16 + qd * 4 + r, s = j * 16 + l16;
        Ps[t * 72 + s] = (t >= s) ? f2bf(pacc[j][r]) : (short)0;
      }
  }
  __syncthreads();

  // o_intra = Ps x vT
  f32x4 oacc[8];
#pragma unroll
  for (int j = 0; j < 8; j++) oacc[j] = (f32x4){0.f, 0.f, 0.f, 0.f};
  {
    const int* vTi = (const int*)vT;
    const int tq = wave * 16 + l16;
#pragma unroll
    for (int ks = 0; ks < 2; ks++) {
      const int ch = ks * 4 + qd;
      const short8 a = *(const short8*)&Ps[tq * 72 + ch * 8];
#pragma unroll
      for (int j = 0; j < 8; j++) {
        const int dv = j * 16 + l16;
        const int ba = dv * 33 + ch * 4;
        short8 bq;
#pragma unroll
        for (int w2 = 0; w2 < 4; w2++) {
          const int v = vTi[ba + w2];
          bq[2 * w2] = (short)(v & 0xffff);
          bq[2 * w2 + 1] = (short)((unsigned)v >> 16);
        }
        oacc[j] =
            __builtin_amdgcn_mfma_f32_16x16x32_bf16(a, bq, oacc[j], 0, 0, 0);
      }
    }
  }
#pragma unroll
  for (int j = 0; j < 8; j++)
#pragma unroll
    for (int r = 0; r < 4; r++) {
      const int t = wave * 16 + qd * 4 + r;
      const int dv = j * 16 + l16;
      bf16_t* p = &attn[rbase + (size_t)t * HIDN + dv];
      if (ACC) *p = (bf16_t)((float)*p + oacc[j][r]);
      else     *p = (bf16_t)oacc[j][r];
    }
}

// ---------------------------------------------------------------------------
// k_s2: sequential chunk combine (swizzled UT rows); S^T in place.
// ---------------------------------------------------------------------------
__global__ __launch_bounds__(256) void k_s2(bf16_t* __restrict__ UT,
                                            const float* __restrict__ Btot) {
  const int dg = blockIdx.x, bh = blockIdx.y;
  const int dv = dg * 8 + (threadIdx.x >> 5);
  const int dk0 = (threadIdx.x & 31) * 4;
  const int pos = dv * 128 + (((dk0 >> 3) ^ (dv & 7)) << 3) + (dk0 & 7);
  float st[4] = {0.f, 0.f, 0.f, 0.f};
  for (int nn = 0; nn < NCHUNK; nn++) {
    short* p = (short*)UT + (size_t)(bh * NCHUNK + nn) * (DD * DD) + pos;
    const float4 bp =
        *(const float4*)(Btot + (size_t)(bh * NCHUNK + nn) * DD + dk0);
    short u0 = p[0], u1 = p[1], u2 = p[2], u3 = p[3];
    p[0] = f2bf(st[0]); p[1] = f2bf(st[1]);
    p[2] = f2bf(st[2]); p[3] = f2bf(st[3]);
    st[0] = st[0] * __expf(bp.x) + bf2f(u0);
    st[1] = st[1] * __expf(bp.y) + bf2f(u1);
    st[2] = st[2] * __expf(bp.z) + bf2f(u2);
    st[3] = st[3] * __expf(bp.w) + bf2f(u3);
  }
}

// ---------------------------------------------------------------------------
// k_s3b: inter-chunk  attn += qh @ S.  S staged via gload16 (async, overlaps
// qh rebuild); both read as swizzled b128 frags.
// ---------------------------------------------------------------------------
__global__ __launch_bounds__(256) void k_s3b(
    const bf16_t* __restrict__ Qb, const bf16_t* __restrict__ Gc,
    const bf16_t* __restrict__ UT, const float* __restrict__ alpha,
    const int e, bf16_t* __restrict__ attn) {
  const int n = blockIdx.x, bh = blockIdx.y;
  const int b = bh >> 4, h = bh & 15;
  const size_t rbase = ((size_t)(b * SEQ + n * CHUNK)) * HIDN + h * DD;
  const int tid = threadIdx.x;
  const int wave = tid >> 6, lane = tid & 63, qd = lane >> 4, l16 = lane & 15;
  __shared__ short qh[64 * 128];
  __shared__ short Ss[128 * 128];
  const float mx = fmaxf(alpha[0], alpha[1]);
  const float x0 = __expf(alpha[0] - mx), x1 = __expf(alpha[1] - mx);
  const float wsc = ((e ? x1 : x0) / (x0 + x1)) * QSCALE;

  // async-stage S tile (2048 x 16B chunks, lane-linear, layout preserved)
  const short* Sp = (const short*)UT + (size_t)(bh * NCHUNK + n) * (DD * DD);
#pragma unroll
  for (int rep = 0; rep < 8; rep++) {
    const int c = rep * 256 + tid;
    gload_lds16(Sp + c * 8, &Ss[c * 8]);
  }
  // qh rebuild (overlaps the async loads)
  const short* Qp = (const short*)Qb;
  const short* Gp = (const short*)Gc;
#pragma unroll
  for (int rep = 0; rep < 4; rep++) {
    const int slot = rep * 256 + tid;
    const int t = slot >> 4, ch = slot & 15;
    const size_t ga = rbase + (size_t)t * HIDN + ch * 8;
    const short8 qq = *(const short8*)(Qp + ga);
    const short8 cc = *(const short8*)(Gp + ga);
    short8 o;
#pragma unroll
    for (int j = 0; j < 8; j++)
      o[j] = f2bf(bf2f(qq[j]) * wsc * __expf(hf2f(cc[j])));
    *(short8*)&qh[t * 128 + ((ch ^ (t & 7)) << 3)] = o;
  }
  __syncthreads();

  f32x4 oacc[8];
#pragma unroll
  for (int j = 0; j < 8; j++) oacc[j] = (f32x4){0.f, 0.f, 0.f, 0.f};
  const int tq = wave * 16 + l16;
#pragma unroll
  for (int ks = 0; ks < 4; ks++) {
    const int ch = ks * 4 + qd;
    const short8 a = *(const short8*)&qh[tq * 128 + ((ch ^ (tq & 7)) << 3)];
#pragma unroll
    for (int j = 0; j < 8; j++) {
      const int dv = j * 16 + l16;
      const short8 bq = *(const short8*)&Ss[dv * 128 + ((ch ^ (dv & 7)) << 3)];
      oacc[j] =
          __builtin_amdgcn_mfma_f32_16x16x32_bf16(a, bq, oacc[j], 0, 0, 0);
    }
  }
#pragma unroll
  for (int j = 0; j < 8; j++)
#pragma unroll
    for (int r = 0; r < 4; r++) {
      const int t = wave * 16 + qd * 4 + r;
      const int dv = j * 16 + l16;
      bf16_t* p = &attn[rbase + (size_t)t * HIDN + dv];
      *p = (bf16_t)((float)*p + oacc[j][r]);
    }
}

// ---------------------------------------------------------------------------
extern "C" void kernel_launch(void* const* d_in, const int* in_sizes, int n_in,
                              void* d_out, int out_size, void* d_ws,
                              size_t ws_size, hipStream_t stream) {
  const float* hid  = (const float*)d_in[0];
  const float* wq   = (const float*)d_in[1];
  const float* wk   = (const float*)d_in[2];
  const float* wv   = (const float*)d_in[3];
  const float* wo   = (const float*)d_in[4];
  const float* wg1  = (const float*)d_in[5];
  const float* bg1  = (const float*)d_in[6];
  const float* wg2  = (const float*)d_in[7];
  const float* bg2  = (const float*)d_in[8];
  const float* alph = (const float*)d_in[9];
  float* out = (float*)d_out;
  (void)in_sizes; (void)n_in; (void)out_size;

  char* ws = (char*)d_ws;
  size_t off = 0;
  auto alloc = [&](size_t bytes) -> void* {
    void* p = ws + off;
    off += (bytes + 255) & ~(size_t)255;
    return p;
  };
  const size_t NEL = NELC, WEL = WELC;
  bf16_t* Xb   = (bf16_t*)alloc(NEL * 2);  // X; reused as attn
  bf16_t* Wcur = (bf16_t*)alloc(WEL * 2);  // Wg2
  bf16_t* WoB  = (bf16_t*)alloc(WEL * 2);  // Wo
  bf16_t* Qb   = (bf16_t*)alloc(NEL * 2);
  bf16_t* Kb   = (bf16_t*)alloc(NEL * 2);
  bf16_t* Vb   = (bf16_t*)alloc(NEL * 2);
  bf16_t* G1b  = (bf16_t*)alloc(NEL * 2);
  bf16_t* G2b  = (bf16_t*)alloc(NEL * 2);
  float*  Btot = (float*) alloc((size_t)2 * NBH * NCHUNK * DD * 4);
  bf16_t* Wd = (bf16_t*)d_out;  // weights, then U/S states, then final out
  bf16_t* UT = (bf16_t*)d_out;

  if (off > ws_size) {  // diagnostic fallback
    k_zero<<<dim3((unsigned)(NEL / 256)), 256, 0, stream>>>(out);
    return;
  }

  k_cvt_all<<<dim3(8192, 7), 256, 0, stream>>>(hid, wq, wk, wv, wg1, wg2, wo,
                                               Xb, Wd, Wcur, WoB);
  k_gemm_proj<<<dim3(16, 16, 5), 512, 0, stream>>>(
      Xb, Wd, Wd + WEL, Wd + 2 * WEL, Wd + 3 * WEL, Wcur, bg1, bg2, Qb, Kb, Vb,
      G1b, G2b);
  k_gc<<<dim3(NCHUNK, BB * 4, 2), 64, 0, stream>>>(G1b, G2b, Btot);

  const dim3 gs(NCHUNK, NBH), g2(16, NBH);
  const size_t BSTRIDE = (size_t)NBH * NCHUNK * DD;
  // e = 0
  k_sA<0><<<gs, 256, 0, stream>>>(Qb, Kb, Vb, G1b, UT, alph, Xb);
  k_s2<<<g2, 256, 0, stream>>>(UT, Btot);
  k_s3b<<<gs, 256, 0, stream>>>(Qb, G1b, UT, alph, 0, Xb);
  // e = 1
  k_sA<1><<<gs, 256, 0, stream>>>(Qb, Kb, Vb, G2b, UT, alph, Xb);
  k_s2<<<g2, 256, 0, stream>>>(UT, Btot + BSTRIDE);
  k_s3b<<<gs, 256, 0, stream>>>(Qb, G2b, UT, alph, 1, Xb);

  k_gemm_out<<<dim3(16, 16), 512, 0, stream>>>(Xb, WoB, out);
}